// Round 5
// baseline (108.855 us; speedup 1.0000x reference)
//
#include <hip/hip_runtime.h>

// WarpV2: out[b,y,x,c] = bilinear(img[b], y + flo[b,y,x,1], x + flo[b,y,x,0])
// TFA dense_image_warp semantics: floor clipped to [0, size-2], alpha to [0,1].
// img [8,256,512,64] f32, flo [8,256,512,2] f32, out [8,256,512,64] f32.
//
// R4: 4 float4 per thread (c4, c4+4, c4+8, c4+12) -> 16 outstanding gathers
// per thread, 4 lanes share one flow value, half the waves. XCD swizzle
// (one image per XCD) and nt load/store retained from R3.

constexpr int B = 8;
constexpr int H = 256;
constexpr int W = 512;
constexpr int C = 64;          // 16 float4 per pixel

typedef float nt_f4 __attribute__((ext_vector_type(4)));
typedef float nt_f2 __attribute__((ext_vector_type(2)));

__device__ __forceinline__ nt_f4 bilerp(float4 tl, float4 tr, float4 bl, float4 br,
                                        float ax, float ay)
{
    nt_f4 r;
    {
        float t = tl.x + ax * (tr.x - tl.x);
        float u = bl.x + ax * (br.x - bl.x);
        r.x = t + ay * (u - t);
    }
    {
        float t = tl.y + ax * (tr.y - tl.y);
        float u = bl.y + ax * (br.y - bl.y);
        r.y = t + ay * (u - t);
    }
    {
        float t = tl.z + ax * (tr.z - tl.z);
        float u = bl.z + ax * (br.z - bl.z);
        r.z = t + ay * (u - t);
    }
    {
        float t = tl.w + ax * (tr.w - tl.w);
        float u = bl.w + ax * (br.w - bl.w);
        r.w = t + ay * (u - t);
    }
    return r;
}

__global__ __launch_bounds__(256) void warp_kernel(
    const float4* __restrict__ img4,
    const nt_f2* __restrict__ flo2,
    nt_f4* __restrict__ out4)
{
    // XCD swizzle: nwg = 16384 (divisible by 8). XCD k (= bid%8) gets the
    // contiguous work range [k*2048, (k+1)*2048) -> exactly batch image k.
    int bid  = blockIdx.x;
    int work = ((bid & 7) << 11) + (bid >> 3);
    int idx  = (work << 8) + threadIdx.x;    // quarter-pixel-row index

    int c4  = idx & 3;           // chunks c4, c4+4, c4+8, c4+12
    int p   = idx >> 2;          // pixel index  ((b*H + y)*W + x)
    int x   = p & (W - 1);
    int y   = (p >> 9) & (H - 1);
    int b   = p >> 17;

    nt_f2 f = __builtin_nontemporal_load(&flo2[p]);  // f.x = dx, f.y = dy
    float qx = (float)x + f.x;
    float qy = (float)y + f.y;

    float fx = floorf(qx); fx = fminf(fmaxf(fx, 0.0f), (float)(W - 2));
    float fy = floorf(qy); fy = fminf(fmaxf(fy, 0.0f), (float)(H - 2));
    float ax = fminf(fmaxf(qx - fx, 0.0f), 1.0f);
    float ay = fminf(fmaxf(qy - fy, 0.0f), 1.0f);
    int ix = (int)fx;
    int iy = (int)fy;

    int base = (((b * H + iy) * W + ix) << 4) + c4;    // float4 units
    const int rowstep = W << 4;

    // 16 independent gathers -> deep MLP per wave
    float4 tl0 = img4[base];
    float4 tr0 = img4[base + 16];
    float4 bl0 = img4[base + rowstep];
    float4 br0 = img4[base + rowstep + 16];
    float4 tl1 = img4[base + 4];
    float4 tr1 = img4[base + 20];
    float4 bl1 = img4[base + rowstep + 4];
    float4 br1 = img4[base + rowstep + 20];
    float4 tl2 = img4[base + 8];
    float4 tr2 = img4[base + 24];
    float4 bl2 = img4[base + rowstep + 8];
    float4 br2 = img4[base + rowstep + 24];
    float4 tl3 = img4[base + 12];
    float4 tr3 = img4[base + 28];
    float4 bl3 = img4[base + rowstep + 12];
    float4 br3 = img4[base + rowstep + 28];

    nt_f4 r0 = bilerp(tl0, tr0, bl0, br0, ax, ay);
    nt_f4 r1 = bilerp(tl1, tr1, bl1, br1, ax, ay);
    nt_f4 r2 = bilerp(tl2, tr2, bl2, br2, ax, ay);
    nt_f4 r3 = bilerp(tl3, tr3, bl3, br3, ax, ay);

    int o = (p << 4) + c4;
    __builtin_nontemporal_store(r0, &out4[o]);
    __builtin_nontemporal_store(r1, &out4[o + 4]);
    __builtin_nontemporal_store(r2, &out4[o + 8]);
    __builtin_nontemporal_store(r3, &out4[o + 12]);
}

extern "C" void kernel_launch(void* const* d_in, const int* in_sizes, int n_in,
                              void* d_out, int out_size, void* d_ws, size_t ws_size,
                              hipStream_t stream)
{
    const float4* img4 = (const float4*)d_in[0];
    const nt_f2*  flo2 = (const nt_f2*)d_in[1];
    nt_f4*        out4 = (nt_f4*)d_out;

    const int total = B * H * W * (C / 16);            // 4,194,304 threads
    dim3 block(256);
    dim3 grid(total / 256);                            // 16384 blocks
    warp_kernel<<<grid, block, 0, stream>>>(img4, flo2, out4);
}

// Round 6
// 93.256 us; speedup vs baseline: 1.1673x; 1.1673x over previous
//
#include <hip/hip_runtime.h>

// WarpV2: out[b,y,x,c] = bilinear(img[b], y + flo[b,y,x,1], x + flo[b,y,x,0])
// TFA dense_image_warp semantics: floor clipped to [0, size-2], alpha to [0,1].
// img [8,256,512,64] f32, flo [8,256,512,2] f32, out [8,256,512,64] f32.
//
// R5 = revert to R3 (best, 92.5us): 2 float4 per thread (c4, c4+8) so each
// gather instr covers a contiguous 128B per 8-lane pixel-group; XCD swizzle
// (one batch image per XCD's L2); nt load for flo, nt store for out.
// R4's 4-float4/thread variant regressed (64B gather granules).

constexpr int B = 8;
constexpr int H = 256;
constexpr int W = 512;
constexpr int C = 64;          // 16 float4 per pixel

typedef float nt_f4 __attribute__((ext_vector_type(4)));
typedef float nt_f2 __attribute__((ext_vector_type(2)));

__device__ __forceinline__ nt_f4 bilerp(float4 tl, float4 tr, float4 bl, float4 br,
                                        float ax, float ay)
{
    nt_f4 r;
    {
        float t = tl.x + ax * (tr.x - tl.x);
        float u = bl.x + ax * (br.x - bl.x);
        r.x = t + ay * (u - t);
    }
    {
        float t = tl.y + ax * (tr.y - tl.y);
        float u = bl.y + ax * (br.y - bl.y);
        r.y = t + ay * (u - t);
    }
    {
        float t = tl.z + ax * (tr.z - tl.z);
        float u = bl.z + ax * (br.z - bl.z);
        r.z = t + ay * (u - t);
    }
    {
        float t = tl.w + ax * (tr.w - tl.w);
        float u = bl.w + ax * (br.w - bl.w);
        r.w = t + ay * (u - t);
    }
    return r;
}

__global__ __launch_bounds__(256) void warp_kernel(
    const float4* __restrict__ img4,
    const nt_f2* __restrict__ flo2,
    nt_f4* __restrict__ out4)
{
    // XCD swizzle: nwg = 32768 (divisible by 8). XCD k (= bid%8) gets the
    // contiguous work range [k*4096, (k+1)*4096) -> exactly batch image k.
    int bid  = blockIdx.x;
    int work = ((bid & 7) << 12) + (bid >> 3);
    int idx  = (work << 8) + threadIdx.x;    // half-pixel-row index

    int c4  = idx & 7;           // this thread covers float4 chunks c4 and c4+8
    int p   = idx >> 3;          // pixel index  ((b*H + y)*W + x)
    int x   = p & (W - 1);
    int y   = (p >> 9) & (H - 1);
    int b   = p >> 17;

    nt_f2 f = __builtin_nontemporal_load(&flo2[p]);  // f.x = dx, f.y = dy
    float qx = (float)x + f.x;
    float qy = (float)y + f.y;

    float fx = floorf(qx); fx = fminf(fmaxf(fx, 0.0f), (float)(W - 2));
    float fy = floorf(qy); fy = fminf(fmaxf(fy, 0.0f), (float)(H - 2));
    float ax = fminf(fmaxf(qx - fx, 0.0f), 1.0f);
    float ay = fminf(fmaxf(qy - fy, 0.0f), 1.0f);
    int ix = (int)fx;
    int iy = (int)fy;

    int base = (((b * H + iy) * W + ix) << 4) + c4;    // float4 units
    const int rowstep = W << 4;

    // 8 independent gathers -> deep MLP per wave
    float4 tl0 = img4[base];
    float4 tr0 = img4[base + 16];
    float4 bl0 = img4[base + rowstep];
    float4 br0 = img4[base + rowstep + 16];
    float4 tl1 = img4[base + 8];
    float4 tr1 = img4[base + 24];
    float4 bl1 = img4[base + rowstep + 8];
    float4 br1 = img4[base + rowstep + 24];

    nt_f4 r0 = bilerp(tl0, tr0, bl0, br0, ax, ay);
    nt_f4 r1 = bilerp(tl1, tr1, bl1, br1, ax, ay);

    int o = (p << 4) + c4;
    __builtin_nontemporal_store(r0, &out4[o]);
    __builtin_nontemporal_store(r1, &out4[o + 8]);
}

extern "C" void kernel_launch(void* const* d_in, const int* in_sizes, int n_in,
                              void* d_out, int out_size, void* d_ws, size_t ws_size,
                              hipStream_t stream)
{
    const float4* img4 = (const float4*)d_in[0];
    const nt_f2*  flo2 = (const nt_f2*)d_in[1];
    nt_f4*        out4 = (nt_f4*)d_out;

    const int total = B * H * W * (C / 8);             // 8,388,608 threads
    dim3 block(256);
    dim3 grid(total / 256);                            // 32768 blocks
    warp_kernel<<<grid, block, 0, stream>>>(img4, flo2, out4);
}